// Round 5
// baseline (127.703 us; speedup 1.0000x reference)
//
#include <hip/hip_runtime.h>
#include <hip/hip_bf16.h>
#include <math.h>

#define FSE_HW    524288   // 512 * 1024
#define FSE_C     512
#define FSE_K     19
#define FSE_NS    8192
#define FSE_SLAB  16                    // channel slabs
#define FSE_CPS   (FSE_C / FSE_SLAB)    // 32 channels per slab

__global__ __launch_bounds__(256) void fse_zero_kernel(float4* __restrict__ out) {
    int i = blockIdx.x * 256 + threadIdx.x;
    out[i] = make_float4(0.f, 0.f, 0.f, 0.f);
}

// ---- stage 1: lane = sample. Each thread owns one sample, loops a 32-channel
// slab. A wave's 64 lanes are 64 CONSECUTIVE sorted samples -> every gather
// instruction reads 64 ascending lines inside one ~16 KB window (max DRAM
// row/bank locality). Partial fp64 sums -> ws (slab-major).
__global__ __launch_bounds__(256) void fse_partial_kernel(
        const float* __restrict__ feats,    // (C, HW)
        const float* __restrict__ protos,   // (K, C)
        const int*   __restrict__ sidx,     // (NS,)
        double*      __restrict__ ws)       // (SLAB, NS, 20)
{
    __shared__ float sPp[FSE_CPS][FSE_K];   // 2432 B

    const int tid  = threadIdx.x;
    const int slab = blockIdx.x & (FSE_SLAB - 1);
    const int sg   = blockIdx.x >> 4;       // 0..31
    const int c0   = slab * FSE_CPS;

    for (int i = tid; i < FSE_CPS * FSE_K; i += 256) {
        const int c = i / FSE_K, k = i % FSE_K;
        sPp[c][k] = protos[k * FSE_C + c0 + c];
    }

    const int sId = sg * 256 + tid;
    const int idx = sidx[sId];              // coalesced
    __syncthreads();

    // 32 independent scattered loads, all in flight; each instruction = one
    // compact 64-line window shared with the wave's 63 neighbor samples
    const float* A = feats + (size_t)c0 * FSE_HW + idx;
    float f[FSE_CPS];
    #pragma unroll
    for (int u = 0; u < FSE_CPS; ++u)
        f[u] = A[(size_t)u * FSE_HW];

    double t[FSE_K];
    #pragma unroll
    for (int k = 0; k < FSE_K; ++k) t[k] = 0.0;
    double f2 = 0.0;

    #pragma unroll
    for (int u = 0; u < FSE_CPS; ++u) {
        const double fd  = (double)f[u];
        f2 = fma(fd, fd, f2);
        const double m2f = -2.0 * fd;                 // exact
        #pragma unroll
        for (int k = 0; k < FSE_K; ++k) {
            const double p = (double)sPp[u][k];       // wave-uniform -> broadcast
            t[k] = fma(p, p + m2f, t[k]);             // p*(p-2f)
        }
    }

    double* W = ws + ((size_t)slab * FSE_NS + sId) * 20;
    #pragma unroll
    for (int k = 0; k < FSE_K; ++k) W[k] = t[k];
    W[19] = f2;
}

// ---- stage 2: sum 16 slab partials, argmax logits, rank, scatter ----
__global__ __launch_bounds__(256) void fse_finalize_kernel(
        const float*  __restrict__ outs,    // (K, HW)
        const int*    __restrict__ sidx,
        const double* __restrict__ ws,      // (SLAB, NS, 20)
        float*        __restrict__ out)     // (HW,)
{
    const int sId = blockIdx.x * 256 + threadIdx.x;   // 0..8191
    const int idx = sidx[sId];

    double t[20];
    {
        const double* W = ws + (size_t)sId * 20;
        #pragma unroll
        for (int j = 0; j < 20; ++j) t[j] = W[j];
    }
    #pragma unroll
    for (int sl = 1; sl < FSE_SLAB; ++sl) {
        const double* W = ws + ((size_t)sl * FSE_NS + sId) * 20;
        #pragma unroll
        for (int j = 0; j < 20; ++j) t[j] += W[j];
    }

    // class argmax (first-max, matches jnp.argmax); consecutive threads ->
    // consecutive samples -> same page-local gather shape
    float best = outs[idx];
    int   ocls = 0;
    #pragma unroll
    for (int k = 1; k < FSE_K; ++k) {
        const float v = outs[(size_t)k * FSE_HW + idx];
        if (v > best) { best = v; ocls = k; }
    }

    const double f2 = t[19];
    double dc = 0.0;
    #pragma unroll
    for (int k = 0; k < FSE_K; ++k) {
        double dk = fmax(f2 + t[k], 1e-12);
        if (k == ocls) dc = dk;
    }
    int rank = 0;
    #pragma unroll
    for (int k = 0; k < FSE_K; ++k) {
        double dk = fmax(f2 + t[k], 1e-12);
        rank += (int)((dk < dc) || (dk == dc && k < ocls));
    }
    out[idx] = (float)rank * (1.0f / 18.0f);
}

// ---- fallback: R2 single kernel (ws too small) --------------------------------
__device__ __forceinline__ int pIdx(int c, int k) { return c * FSE_K + k + (c >> 5); }

__global__ __launch_bounds__(256) void fse_main_kernel(
        const float* __restrict__ feats, const float* __restrict__ outs,
        const float* __restrict__ protos, const int* __restrict__ sidx,
        float* __restrict__ out)
{
    __shared__ float  sP[FSE_C * FSE_K + 16];
    __shared__ float  sLog[16 * FSE_K];
    __shared__ int    sIdx[16];
    __shared__ double sRed[4][16 * 20];

    const int tid = threadIdx.x;
    if (tid < 16) sIdx[tid] = sidx[blockIdx.x * 16 + tid];
    for (int i = tid; i < FSE_K * FSE_C; i += 256) {
        const int k = i / FSE_C, c = i % FSE_C;
        sP[pIdx(c, k)] = protos[i];
    }
    __syncthreads();
    for (int i = tid; i < 16 * FSE_K; i += 256) {
        const int s = i / FSE_K, k = i % FSE_K;
        sLog[i] = outs[(size_t)k * FSE_HW + sIdx[s]];
    }
    const int wave = tid >> 6, lane = tid & 63;
    const int s = lane & 15, q = lane >> 4;
    const int c0 = wave * 128 + q * 32;
    const float* A = feats + (size_t)c0 * FSE_HW + sIdx[s];
    double t[FSE_K];
    #pragma unroll
    for (int k = 0; k < FSE_K; ++k) t[k] = 0.0;
    double f2 = 0.0;
    #pragma unroll
    for (int j8 = 0; j8 < 4; ++j8) {
        float f[8];
        #pragma unroll
        for (int u = 0; u < 8; ++u) f[u] = A[(size_t)(j8 * 8 + u) * FSE_HW];
        #pragma unroll
        for (int u = 0; u < 8; ++u) {
            const int c = c0 + j8 * 8 + u;
            const double fd = (double)f[u];
            f2 = fma(fd, fd, f2);
            const double m2f = -2.0 * fd;
            #pragma unroll
            for (int k = 0; k < FSE_K; ++k) {
                const double p = (double)sP[pIdx(c, k)];
                t[k] = fma(p, p + m2f, t[k]);
            }
        }
    }
    #pragma unroll
    for (int k = 0; k < FSE_K; ++k) { t[k] += __shfl_xor(t[k], 16); t[k] += __shfl_xor(t[k], 32); }
    f2 += __shfl_xor(f2, 16); f2 += __shfl_xor(f2, 32);
    if (lane < 16) {
        #pragma unroll
        for (int k = 0; k < FSE_K; ++k) sRed[wave][s * 20 + k] = t[k];
        sRed[wave][s * 20 + 19] = f2;
    }
    __syncthreads();
    for (int cell = tid; cell < 16 * 20; cell += 256)
        sRed[0][cell] = (sRed[0][cell] + sRed[1][cell]) + (sRed[2][cell] + sRed[3][cell]);
    __syncthreads();
    if (tid < 16) {
        const int ss = tid;
        float best = sLog[ss * FSE_K];
        int ocls = 0;
        #pragma unroll
        for (int k = 1; k < FSE_K; ++k) {
            const float v = sLog[ss * FSE_K + k];
            if (v > best) { best = v; ocls = k; }
        }
        const double f2s = sRed[0][ss * 20 + 19];
        double dc = 0.0;
        #pragma unroll
        for (int k = 0; k < FSE_K; ++k) {
            double dk = fmax(f2s + sRed[0][ss * 20 + k], 1e-12);
            if (k == ocls) dc = dk;
        }
        int rank = 0;
        #pragma unroll
        for (int k = 0; k < FSE_K; ++k) {
            double dk = fmax(f2s + sRed[0][ss * 20 + k], 1e-12);
            rank += (int)((dk < dc) || (dk == dc && k < ocls));
        }
        out[sIdx[ss]] = (float)rank * (1.0f / 18.0f);
    }
}

extern "C" void kernel_launch(void* const* d_in, const int* in_sizes, int n_in,
                              void* d_out, int out_size, void* d_ws, size_t ws_size,
                              hipStream_t stream) {
    const float* feats  = (const float*)d_in[0];
    const float* outs   = (const float*)d_in[1];
    const float* protos = (const float*)d_in[2];
    const int*   sidx   = (const int*)d_in[3];
    float* out = (float*)d_out;

    fse_zero_kernel<<<FSE_HW / 4 / 256, 256, 0, stream>>>((float4*)out);

    const size_t ws_need = (size_t)FSE_SLAB * FSE_NS * 20 * sizeof(double);  // ~21 MB
    if (ws_size >= ws_need) {
        fse_partial_kernel<<<FSE_SLAB * (FSE_NS / 256), 256, 0, stream>>>(
            feats, protos, sidx, (double*)d_ws);
        fse_finalize_kernel<<<FSE_NS / 256, 256, 0, stream>>>(
            outs, sidx, (const double*)d_ws, out);
    } else {
        fse_main_kernel<<<FSE_NS / 16, 256, 0, stream>>>(feats, outs, protos, sidx, out);
    }
}

// Round 6
// 98.885 us; speedup vs baseline: 1.2914x; 1.2914x over previous
//
#include <hip/hip_runtime.h>
#include <hip/hip_bf16.h>
#include <math.h>

#define FSE_HW   524288   // 512 * 1024
#define FSE_C    512
#define FSE_K    19
#define FSE_NS   8192
#define FSE_GS   16                  // samples per block
#define FSE_SG   (FSE_NS / FSE_GS)   // 512 blocks

// skewed prototype index: keeps the 4 concurrent channel-groups (c spaced 32)
// on distinct banks: addr diff = 32*19+1 = 609 ≡ 1 (mod 32)
__device__ __forceinline__ int pIdx(int c, int k) { return c * FSE_K + k + (c >> 5); }

__global__ __launch_bounds__(256) void fse_zero_kernel(float4* __restrict__ out) {
    int i = blockIdx.x * 256 + threadIdx.x;
    out[i] = make_float4(0.f, 0.f, 0.f, 0.f);
}

__global__ __launch_bounds__(256) void fse_main_kernel(
        const float* __restrict__ feats,    // (C, HW)
        const float* __restrict__ outs,     // (K, HW)
        const float* __restrict__ protos,   // (K, C)
        const int*   __restrict__ sidx,     // (NS,)
        float* __restrict__ out)            // (HW,)
{
    __shared__ float  sP[FSE_C * FSE_K + 16];      // transposed+skewed protos, ~39 KB
    __shared__ float  sLog[FSE_GS * FSE_K];        // gathered class logits
    __shared__ int    sIdx[FSE_GS];
    __shared__ double sRed[4][FSE_GS][20];         // per-wave partials, 10 KB

    const int tid = threadIdx.x;
    const int g   = blockIdx.x;

    if (tid < FSE_GS) sIdx[tid] = sidx[g * FSE_GS + tid];

    // class-logit gather FIRST (indices straight from global; overlaps staging)
    for (int i = tid; i < FSE_GS * FSE_K; i += 256) {
        const int s = i / FSE_K, k = i % FSE_K;
        sLog[i] = outs[(size_t)k * FSE_HW + sidx[g * FSE_GS + s]];
    }

    // stage prototypes transposed+skewed (coalesced read)
    for (int i = tid; i < FSE_K * FSE_C; i += 256) {
        const int k = i / FSE_C, c = i % FSE_C;
        sP[pIdx(c, k)] = protos[i];
    }
    __syncthreads();   // sIdx, sLog, sP all visible

    // lane = sample(4b) | channel-quarter(2b); wave owns 128 channels
    const int wave = tid >> 6, lane = tid & 63;
    const int s  = lane & 15;
    const int q  = lane >> 4;
    const int c0 = wave * 128 + q * 32;
    const float* A = feats + (size_t)c0 * FSE_HW + sIdx[s];

    double t[FSE_K];
    #pragma unroll
    for (int k = 0; k < FSE_K; ++k) t[k] = 0.0;
    double f2 = 0.0;

    #pragma unroll
    for (int j8 = 0; j8 < 4; ++j8) {           // 32 channels per lane, 8 at a time
        float f[8];
        #pragma unroll
        for (int u = 0; u < 8; ++u)
            f[u] = A[(size_t)(j8 * 8 + u) * FSE_HW];
        #pragma unroll
        for (int u = 0; u < 8; ++u) {
            const int c = c0 + j8 * 8 + u;
            const double fd  = (double)f[u];
            f2 = fma(fd, fd, f2);
            const double m2f = -2.0 * fd;       // exact
            #pragma unroll
            for (int k = 0; k < FSE_K; ++k) {
                const double p = (double)sP[pIdx(c, k)];   // 16-lane broadcast
                t[k] = fma(p, p + m2f, t[k]);              // p*(p-2f)
            }
        }
    }

    // reduce the 4 channel-quarters within the wave
    #pragma unroll
    for (int k = 0; k < FSE_K; ++k) {
        t[k] += __shfl_xor(t[k], 16);
        t[k] += __shfl_xor(t[k], 32);
    }
    f2 += __shfl_xor(f2, 16);
    f2 += __shfl_xor(f2, 32);

    if (lane < FSE_GS) {
        #pragma unroll
        for (int k = 0; k < FSE_K; ++k) sRed[wave][s][k] = t[k];
        sRed[wave][s][19] = f2;
    }
    __syncthreads();

    // sum the 4 waves' partials (deterministic order)
    for (int cell = tid; cell < FSE_GS * 20; cell += 256) {
        const int ss = cell / 20, j = cell % 20;
        sRed[0][ss][j] = (sRed[0][ss][j] + sRed[1][ss][j])
                       + (sRed[2][ss][j] + sRed[3][ss][j]);
    }
    __syncthreads();

    // ---- rank + scatter (one thread per sample) ----
    if (tid < FSE_GS) {
        const int ss = tid;
        float best = sLog[ss * FSE_K];
        int   ocls = 0;
        #pragma unroll
        for (int k = 1; k < FSE_K; ++k) {       // first-max, matches jnp.argmax
            const float v = sLog[ss * FSE_K + k];
            if (v > best) { best = v; ocls = k; }
        }
        const double f2s = sRed[0][ss][19];
        double dc = 0.0;
        #pragma unroll
        for (int k = 0; k < FSE_K; ++k) {
            double dk = fmax(f2s + sRed[0][ss][k], 1e-12);
            if (k == ocls) dc = dk;
        }
        int rank = 0;
        #pragma unroll
        for (int k = 0; k < FSE_K; ++k) {
            double dk = fmax(f2s + sRed[0][ss][k], 1e-12);
            rank += (int)((dk < dc) || (dk == dc && k < ocls));
        }
        out[sIdx[ss]] = (float)rank * (1.0f / 18.0f);
    }
}

extern "C" void kernel_launch(void* const* d_in, const int* in_sizes, int n_in,
                              void* d_out, int out_size, void* d_ws, size_t ws_size,
                              hipStream_t stream) {
    const float* feats  = (const float*)d_in[0];
    const float* outs   = (const float*)d_in[1];
    const float* protos = (const float*)d_in[2];
    const int*   sidx   = (const int*)d_in[3];
    float* out = (float*)d_out;

    fse_zero_kernel<<<FSE_HW / 4 / 256, 256, 0, stream>>>((float4*)out);
    fse_main_kernel<<<FSE_SG, 256, 0, stream>>>(feats, outs, protos, sidx, out);
}